// Round 1
// baseline (1452.565 us; speedup 1.0000x reference)
//
#include <hip/hip_runtime.h>
#include <hip/hip_bf16.h>

#define AS1 __attribute__((address_space(1)))
#define AS3 __attribute__((address_space(3)))

typedef __attribute__((ext_vector_type(4))) float f32x4;
typedef __attribute__((ext_vector_type(8))) short b16x8;     // 8 bf16 (4 VGPRs) MFMA operand
typedef __attribute__((ext_vector_type(8))) unsigned short u16x8;
typedef unsigned short u16;

static __device__ __forceinline__ u16 f2b(float f) {
  return __builtin_bit_cast(u16, __float2bfloat16(f));
}
static __device__ __forceinline__ float b2f(u16 u) {
  unsigned v = ((unsigned)u) << 16;
  return __builtin_bit_cast(float, v);
}
static __device__ __forceinline__ void gl2lds16(const u16* g, u16* l) {
  __builtin_amdgcn_global_load_lds((const AS1 void*)g, (AS3 void*)l, 16, 0, 0);
}

// ---------------- fp32 -> bf16 convert, 8 elems/thread ----------------
__global__ void k_cvt(const float* __restrict__ s, u16* __restrict__ d, long n) {
  long i = ((long)blockIdx.x * 256 + threadIdx.x) * 8;
  if (i >= n) return;
  float4 a = *(const float4*)(s + i);
  float4 b = *(const float4*)(s + i + 4);
  u16x8 o;
  o[0] = f2b(a.x); o[1] = f2b(a.y); o[2] = f2b(a.z); o[3] = f2b(a.w);
  o[4] = f2b(b.x); o[5] = f2b(b.y); o[6] = f2b(b.z); o[7] = f2b(b.w);
  *(u16x8*)(d + i) = o;
}

// ------- RPE tables: out[h][r(240)][d(32)] = bf16(src[(d*32+h)*225 + r]), r>=225 -> 0 -------
__global__ void k_rpe(const float* __restrict__ rq, const float* __restrict__ rk,
                      u16* __restrict__ oq, u16* __restrict__ ok) {
  int h = blockIdx.y;
  int r = blockIdx.x * 8 + (threadIdx.x >> 5);
  int d = threadIdx.x & 31;
  const float* s = blockIdx.z ? rk : rq;
  u16* o = blockIdx.z ? ok : oq;
  float v = (r < 225) ? s[(d * 32 + h) * 225 + r] : 0.f;
  o[(h * 240 + r) * 32 + d] = f2b(v);
}

// ---------------- 128x128 tile GEMM, BK=64, global_load_lds staging ----------------
// A[M][1024] bf16 row-major (k contiguous), Bw[N][1024] bf16 (n-major, k contiguous).
// MODE 0: qkv epilogue -> per-head layout (+bias, V transposed). MODE 1: fp32 out + bias.
template <int MODE>
__global__ __launch_bounds__(256) void k_gemm(
    const u16* __restrict__ A, const u16* __restrict__ Bw,
    const float* __restrict__ b0, const float* __restrict__ b1, const float* __restrict__ b2,
    u16* __restrict__ oq, float* __restrict__ of) {
  __shared__ alignas(16) u16 lA[128 * 64];
  __shared__ alignas(16) u16 lB[128 * 64];
  const int l = threadIdx.x & 63, w = threadIdx.x >> 6;
  const int lo = l & 15, hi = l >> 4;
  const int tn = blockIdx.x * 128, tm = blockIdx.y * 128;

  // staging: chunk c = w*4+j covers rows c*8..c*8+7; lane i -> row c*8+(i>>3), col (i&7)*8
  const int srow = w * 32 + (l >> 3);
  const int scol = (l & 7) * 8;
  const u16* gA = A + (size_t)(tm + srow) * 1024 + scol;
  const u16* gB = Bw + (size_t)(tn + srow) * 1024 + scol;

  f32x4 acc[4][4];
#pragma unroll
  for (int i = 0; i < 4; ++i)
#pragma unroll
    for (int j = 0; j < 4; ++j) acc[i][j] = (f32x4){0.f, 0.f, 0.f, 0.f};

  const int ar = (w >> 1) * 64 + lo;  // wave row origin in tile + frag row
  const int br = (w & 1) * 64 + lo;

  for (int kk = 0; kk < 1024; kk += 64) {
#pragma unroll
    for (int j = 0; j < 4; ++j) {
      gl2lds16(gA + (size_t)j * 8192 + kk, lA + (w * 4 + j) * 512);
      gl2lds16(gB + (size_t)j * 8192 + kk, lB + (w * 4 + j) * 512);
    }
    __syncthreads();
#pragma unroll
    for (int ks = 0; ks < 2; ++ks) {
      b16x8 af[4], bfr[4];
#pragma unroll
      for (int t = 0; t < 4; ++t)
        af[t] = *(const b16x8*)(lA + (ar + t * 16) * 64 + ks * 32 + hi * 8);
#pragma unroll
      for (int t = 0; t < 4; ++t)
        bfr[t] = *(const b16x8*)(lB + (br + t * 16) * 64 + ks * 32 + hi * 8);
#pragma unroll
      for (int i = 0; i < 4; ++i)
#pragma unroll
        for (int j = 0; j < 4; ++j)
          acc[i][j] = __builtin_amdgcn_mfma_f32_16x16x32_bf16(af[i], bfr[j], acc[i][j], 0, 0, 0);
    }
    __syncthreads();
  }

  const int wr = w >> 1, wc = w & 1;
  if (MODE == 0) {
    const size_t G = 67108864;  // 1024*32*64*32 elements per q/k/v plane
    const int g = tn >> 10;     // 0:q 1:k 2:v (128 | 1024, so uniform per block)
    const float* bias = (g == 0) ? b0 : (g == 1) ? b1 : b2;
#pragma unroll
    for (int i = 0; i < 4; ++i)
#pragma unroll
      for (int j = 0; j < 4; ++j)
#pragma unroll
        for (int r = 0; r < 4; ++r) {
          int m = tm + wr * 64 + i * 16 + hi * 4 + r;  // C/D: row=(l>>4)*4+reg
          int n = tn + wc * 64 + j * 16 + lo;          //      col=l&15
          int nn = n & 1023;
          float v = acc[i][j][r] + bias[nn];
          int h = nn >> 5, hd = nn & 31, b = m >> 6, s = m & 63;
          size_t dst;
          if (g < 2)
            dst = (size_t)g * G + ((size_t)(b * 32 + h) * 64 + s) * 32 + hd;  // [b][h][s][hd]
          else
            dst = 2 * G + ((size_t)(b * 32 + h) * 32 + hd) * 64 + s;          // V^T: [b][h][hd][s]
          oq[dst] = f2b(v);
        }
  } else {
#pragma unroll
    for (int i = 0; i < 4; ++i)
#pragma unroll
      for (int j = 0; j < 4; ++j)
#pragma unroll
        for (int r = 0; r < 4; ++r) {
          int m = tm + wr * 64 + i * 16 + hi * 4 + r;
          int n = tn + wc * 64 + j * 16 + lo;
          of[(size_t)m * 1024 + n] = acc[i][j][r] + b0[n];
        }
  }
}

// ---------------- attention: one (b,h) per 256-thread block, wave w owns q-rows [w*16, w*16+16) --
__global__ __launch_bounds__(256) void k_attn(
    const u16* __restrict__ qkv, const u16* __restrict__ rq,
    const u16* __restrict__ rk, u16* __restrict__ att) {
  __shared__ alignas(16) u16 buf[64 * 244];  // Bq then Bk boards (bf16), rows padded to 244
  __shared__ alignas(16) u16 pl[64 * 72];    // P (exp scores) bf16, padded rows
  const int l = threadIdx.x & 63, w = threadIdx.x >> 6;
  const int lo = l & 15, hi = l >> 4;
  const int b = blockIdx.x, h = blockIdx.y;
  const size_t G = 67108864;
  const u16* qp = qkv + (size_t)(b * 32 + h) * 2048;          // [64][32]
  const u16* kp = qkv + G + (size_t)(b * 32 + h) * 2048;      // [64][32]
  const u16* vp = qkv + 2 * G + (size_t)(b * 32 + h) * 2048;  // V^T [32][64]

  // Q fragment (A-operand): rows w*16+lo, d = hi*8..+8
  b16x8 qf = *(const b16x8*)(qp + (w * 16 + lo) * 32 + hi * 8);

  // Phase 1: QK^T  (B-operand: lane holds K[kt*16+lo][d contiguous])
  f32x4 s0[4];
#pragma unroll
  for (int kt = 0; kt < 4; ++kt) {
    b16x8 kf = *(const b16x8*)(kp + (kt * 16 + lo) * 32 + hi * 8);
    f32x4 z = (f32x4){0.f, 0.f, 0.f, 0.f};
    s0[kt] = __builtin_amdgcn_mfma_f32_16x16x32_bf16(qf, kf, z, 0, 0, 0);
  }

  // Phase 2: Bq = Q @ Rq[h]^T -> buf rows w*16.. (wave-private)
  const u16* rqh = rq + (size_t)h * 7680;  // 240*32
#pragma unroll
  for (int nt = 0; nt < 15; ++nt) {
    b16x8 rf = *(const b16x8*)(rqh + (nt * 16 + lo) * 32 + hi * 8);
    f32x4 z = (f32x4){0.f, 0.f, 0.f, 0.f};
    f32x4 c = __builtin_amdgcn_mfma_f32_16x16x32_bf16(qf, rf, z, 0, 0, 0);
#pragma unroll
    for (int r = 0; r < 4; ++r) buf[(w * 16 + hi * 4 + r) * 244 + nt * 16 + lo] = f2b(c[r]);
  }
  // Phase 3: gather Bq (reads only this wave's rows; same-wave LDS RAW -> lgkmcnt)
#pragma unroll
  for (int kt = 0; kt < 4; ++kt)
#pragma unroll
    for (int r = 0; r < 4; ++r) {
      int q = w * 16 + hi * 4 + r, k = kt * 16 + lo;
      int rel = 15 * ((q >> 3) - (k >> 3) + 7) + (q & 7) - (k & 7) + 7;
      s0[kt][r] += b2f(buf[q * 244 + rel]);
    }

  // Phase 4: Bk = K @ Rk[h]^T -> buf rows w*16.. (overwrites own rows only)
  b16x8 kfa = *(const b16x8*)(kp + (w * 16 + lo) * 32 + hi * 8);
  const u16* rkh = rk + (size_t)h * 7680;
#pragma unroll
  for (int nt = 0; nt < 15; ++nt) {
    b16x8 rf = *(const b16x8*)(rkh + (nt * 16 + lo) * 32 + hi * 8);
    f32x4 z = (f32x4){0.f, 0.f, 0.f, 0.f};
    f32x4 c = __builtin_amdgcn_mfma_f32_16x16x32_bf16(kfa, rf, z, 0, 0, 0);
#pragma unroll
    for (int r = 0; r < 4; ++r) buf[(w * 16 + hi * 4 + r) * 244 + nt * 16 + lo] = f2b(c[r]);
  }
  __syncthreads();  // Bk board read cross-wave below
  // Phase 5: gather Bk (indexed by k row -> all rows)
#pragma unroll
  for (int kt = 0; kt < 4; ++kt)
#pragma unroll
    for (int r = 0; r < 4; ++r) {
      int q = w * 16 + hi * 4 + r, k = kt * 16 + lo;
      int rel = 15 * ((q >> 3) - (k >> 3) + 7) + (q & 7) - (k & 7) + 7;
      s0[kt][r] += b2f(buf[k * 244 + rel]);
    }

  // Phase 6: scale + softmax (rows live in 16-lane groups; reduce over xor 1,2,4,8)
  const float sc = 0.17677669529663689f;  // 1/sqrt(32)
#pragma unroll
  for (int kt = 0; kt < 4; ++kt) s0[kt] *= sc;
  float p[4][4], rsum[4];
#pragma unroll
  for (int r = 0; r < 4; ++r) {
    float m = s0[0][r];
    m = fmaxf(m, s0[1][r]); m = fmaxf(m, s0[2][r]); m = fmaxf(m, s0[3][r]);
    m = fmaxf(m, __shfl_xor(m, 1));
    m = fmaxf(m, __shfl_xor(m, 2));
    m = fmaxf(m, __shfl_xor(m, 4));
    m = fmaxf(m, __shfl_xor(m, 8));
    float sum = 0.f;
#pragma unroll
    for (int kt = 0; kt < 4; ++kt) {
      float e = __expf(s0[kt][r] - m);
      p[kt][r] = e;
      sum += e;
    }
    sum += __shfl_xor(sum, 1);
    sum += __shfl_xor(sum, 2);
    sum += __shfl_xor(sum, 4);
    sum += __shfl_xor(sum, 8);
    rsum[r] = 1.f / sum;
  }

  // Phase 7: P -> LDS (wave-private rows; normalization deferred to output)
#pragma unroll
  for (int kt = 0; kt < 4; ++kt)
#pragma unroll
    for (int r = 0; r < 4; ++r) pl[(w * 16 + hi * 4 + r) * 72 + kt * 16 + lo] = f2b(p[kt][r]);

  // Phase 8: O = P @ V   (A: P rows w*16+lo; B: V^T rows hd, k contiguous)
  f32x4 o0 = (f32x4){0.f, 0.f, 0.f, 0.f}, o1 = (f32x4){0.f, 0.f, 0.f, 0.f};
#pragma unroll
  for (int ks = 0; ks < 2; ++ks) {
    b16x8 pa = *(const b16x8*)(pl + (w * 16 + lo) * 72 + ks * 32 + hi * 8);
    b16x8 v0 = *(const b16x8*)(vp + lo * 64 + ks * 32 + hi * 8);
    b16x8 v1 = *(const b16x8*)(vp + (16 + lo) * 64 + ks * 32 + hi * 8);
    o0 = __builtin_amdgcn_mfma_f32_16x16x32_bf16(pa, v0, o0, 0, 0, 0);
    o1 = __builtin_amdgcn_mfma_f32_16x16x32_bf16(pa, v1, o1, 0, 0, 0);
  }

  // Phase 9: write att[b][s][h*32+hd] (bf16), scaled by 1/rowsum
#pragma unroll
  for (int r = 0; r < 4; ++r) {
    int q = w * 16 + hi * 4 + r;
    size_t base = (size_t)(b * 64 + q) * 1024 + h * 32;
    att[base + lo] = f2b(o0[r] * rsum[r]);
    att[base + 16 + lo] = f2b(o1[r] * rsum[r]);
  }
}

extern "C" void kernel_launch(void* const* d_in, const int* in_sizes, int n_in,
                              void* d_out, int out_size, void* d_ws, size_t ws_size,
                              hipStream_t stream) {
  const float* x   = (const float*)d_in[0];
  const float* qw  = (const float*)d_in[1];
  const float* qb  = (const float*)d_in[2];
  const float* kw  = (const float*)d_in[3];
  const float* kb  = (const float*)d_in[4];
  const float* vw  = (const float*)d_in[5];
  const float* vb  = (const float*)d_in[6];
  const float* ow  = (const float*)d_in[7];
  const float* ob  = (const float*)d_in[8];
  const float* rqw = (const float*)d_in[9];
  const float* rkw = (const float*)d_in[10];

  // workspace layout (total 680,460,288 bytes)
  if (ws_size < 680460288ULL) return;  // diagnostic: leaves d_out zeroed -> absmax == max|ref|
  char* p = (char*)d_ws;
  u16* ws_x   = (u16*)p; p += (size_t)65536 * 1024 * 2;      // x bf16
  u16* ws_w   = (u16*)p; p += (size_t)3 * 1024 * 1024 * 2;   // qkv weights bf16 [3072][1024]
  u16* ws_wo  = (u16*)p; p += (size_t)1024 * 1024 * 2;       // out_w bf16
  u16* ws_rq  = (u16*)p; p += (size_t)32 * 240 * 32 * 2;     // Rq [h][r][d]
  u16* ws_rk  = (u16*)p; p += (size_t)32 * 240 * 32 * 2;     // Rk [h][r][d]
  u16* ws_qkv = (u16*)p; p += (size_t)3 * 67108864 * 2;      // q,k [b][h][s][hd]; v [b][h][hd][s]
  u16* ws_att = (u16*)p; p += (size_t)65536 * 1024 * 2;      // attention out [b*s][1024]

  k_cvt<<<32768, 256, 0, stream>>>(x, ws_x, 67108864L);
  k_cvt<<<512, 256, 0, stream>>>(qw, ws_w, 1048576L);
  k_cvt<<<512, 256, 0, stream>>>(kw, ws_w + 1048576, 1048576L);
  k_cvt<<<512, 256, 0, stream>>>(vw, ws_w + 2097152, 1048576L);
  k_cvt<<<512, 256, 0, stream>>>(ow, ws_wo, 1048576L);
  k_rpe<<<dim3(30, 32, 2), 256, 0, stream>>>(rqw, rkw, ws_rq, ws_rk);

  // QKV projection: grid.x = n-tiles (fastest) so consecutive blocks share the A-tile
  k_gemm<0><<<dim3(24, 512), 256, 0, stream>>>(ws_x, ws_w, qb, kb, vb, ws_qkv, nullptr);
  // attention: grid.x = b (fastest) so consecutive blocks reuse Rq[h]/Rk[h] in cache
  k_attn<<<dim3(1024, 32), 256, 0, stream>>>(ws_qkv, ws_rq, ws_rk, ws_att);
  // output projection
  k_gemm<1><<<dim3(8, 512), 256, 0, stream>>>(ws_att, ws_wo, ob, nullptr, nullptr, nullptr,
                                              (float*)d_out);
}

// Round 2
// 1033.881 us; speedup vs baseline: 1.4050x; 1.4050x over previous
//
#include <hip/hip_runtime.h>
#include <hip/hip_bf16.h>

#define AS1 __attribute__((address_space(1)))
#define AS3 __attribute__((address_space(3)))

typedef __attribute__((ext_vector_type(4))) float f32x4;
typedef __attribute__((ext_vector_type(8))) short b16x8;     // 8 bf16 (4 VGPRs) MFMA operand
typedef __attribute__((ext_vector_type(8))) unsigned short u16x8;
typedef unsigned short u16;

static __device__ __forceinline__ u16 f2b(float f) {
  return __builtin_bit_cast(u16, __float2bfloat16(f));
}
static __device__ __forceinline__ float b2f(u16 u) {
  unsigned v = ((unsigned)u) << 16;
  return __builtin_bit_cast(float, v);
}
static __device__ __forceinline__ void gl2lds16(const u16* g, u16* l) {
  __builtin_amdgcn_global_load_lds((const AS1 void*)g, (AS3 void*)l, 16, 0, 0);
}

// ---------------- fp32 -> bf16 convert, 8 elems/thread ----------------
__global__ void k_cvt(const float* __restrict__ s, u16* __restrict__ d, long n) {
  long i = ((long)blockIdx.x * 256 + threadIdx.x) * 8;
  if (i >= n) return;
  float4 a = *(const float4*)(s + i);
  float4 b = *(const float4*)(s + i + 4);
  u16x8 o;
  o[0] = f2b(a.x); o[1] = f2b(a.y); o[2] = f2b(a.z); o[3] = f2b(a.w);
  o[4] = f2b(b.x); o[5] = f2b(b.y); o[6] = f2b(b.z); o[7] = f2b(b.w);
  *(u16x8*)(d + i) = o;
}

// ------- RPE tables: out[h][r(240)][d(32)] = bf16(src[(d*32+h)*225 + r]), r>=225 -> 0 -------
__global__ void k_rpe(const float* __restrict__ rq, const float* __restrict__ rk,
                      u16* __restrict__ oq, u16* __restrict__ ok) {
  int h = blockIdx.y;
  int r = blockIdx.x * 8 + (threadIdx.x >> 5);
  int d = threadIdx.x & 31;
  const float* s = blockIdx.z ? rk : rq;
  u16* o = blockIdx.z ? ok : oq;
  float v = (r < 225) ? s[(d * 32 + h) * 225 + r] : 0.f;
  o[(h * 240 + r) * 32 + d] = f2b(v);
}

// ---------------- 256x256 tile GEMM, BK=32, 4-deep counted-vmcnt pipeline ----------------
// A[M][1024] bf16 (k contiguous), Bw[N][1024] bf16 (n-major, k contiguous).
// 512 threads = 8 waves (2M x 4N); per-wave output 128x64.
// LDS: 4 circular buffers x (A 256x32 + B 256x32) bf16 = 128 KiB.
// XOR swizzle (both sides, rule 21): storage o = p*64+slot'*8+e; logical slot = slot'^(p&7);
//   row = 2p+(slot>>2); k = (slot&3)*8. Staging pre-swizzles the GLOBAL source per lane
//   (LDS dest stays linear lane*16B); reads apply the same involution -> 2-way conflicts.
// MODE 0: qkv epilogue -> per-head layout (+bias, V transposed). MODE 1: fp32 out + bias.
template <int MODE>
__global__ __launch_bounds__(512) void k_gemm(
    const u16* __restrict__ A, const u16* __restrict__ Bw,
    const float* __restrict__ b0, const float* __restrict__ b1, const float* __restrict__ b2,
    u16* __restrict__ oq, float* __restrict__ of) {
  __shared__ alignas(16) u16 lds[4][16384];  // [buf][A:0..8191 | B:8192..16383]
  const int tid = threadIdx.x;
  const int l = tid & 63, w = tid >> 6;
  const int lo = l & 15, hi = l >> 4;
  const int wr = w >> 2, wc = w & 3;

  // bijective XCD swizzle (nwg % 8 == 0 for both grids)
  const int nbx = gridDim.x;
  const int nb = nbx * gridDim.y;
  const int bid = blockIdx.y * nbx + blockIdx.x;
  const int ord = (bid & 7) * (nb >> 3) + (bid >> 3);
  const int tn = (ord % nbx) * 256, tm = (ord / nbx) * 256;

  // staging lane map: pre-swizzled global source, linear LDS dest (lane*16B)
  const int sl = (tid & 7) ^ ((tid >> 3) & 7);   // logical slot this lane's dest holds
  const int srow = 2 * (tid >> 3) + (sl >> 2);   // row within half-tile (q=0); q=1 adds 128
  const int scol = (sl & 3) * 8;
  const u16* gA = A + (size_t)(tm + srow) * 1024 + scol;
  const u16* gB = Bw + (size_t)(tn + srow) * 1024 + scol;
  u16* dst = &lds[0][0] + tid * 8;

  // fragment-read lane constants (same involution)
  const int p7 = (lo >> 1) & 7;
  const int slr = ((lo & 1) * 4 + hi) ^ p7;
  const int aoff = wr * 4096 + (lo >> 1) * 64 + slr * 8;
  const int boff = 8192 + wc * 2048 + (lo >> 1) * 64 + slr * 8;

  f32x4 acc[8][4];
#pragma unroll
  for (int i = 0; i < 8; ++i)
#pragma unroll
    for (int j = 0; j < 4; ++j) acc[i][j] = (f32x4){0.f, 0.f, 0.f, 0.f};

#define STG(kt) { const int kc = (kt) * 32; u16* d = dst + ((kt) & 3) * 16384; \
    gl2lds16(gA + kc, d);           gl2lds16(gA + 131072 + kc, d + 4096); \
    gl2lds16(gB + kc, d + 8192);    gl2lds16(gB + 131072 + kc, d + 12288); }

  STG(0) STG(1) STG(2)
  asm volatile("s_waitcnt vmcnt(8)" ::: "memory");  // tile 0 landed; 1,2 in flight
  __builtin_amdgcn_s_barrier();
  asm volatile("" ::: "memory");

#pragma unroll 4
  for (int kt = 0; kt < 32; ++kt) {
    if (kt < 29) STG(kt + 3);
    const u16* bufA = &lds[kt & 3][0] + aoff;
    const u16* bufB = &lds[kt & 3][0] + boff;
    b16x8 af[8], bf[4];
#pragma unroll
    for (int i = 0; i < 8; ++i) af[i] = *(const b16x8*)(bufA + i * 512);
#pragma unroll
    for (int j = 0; j < 4; ++j) bf[j] = *(const b16x8*)(bufB + j * 512);
    __builtin_amdgcn_s_setprio(1);
#pragma unroll
    for (int i = 0; i < 8; ++i)
#pragma unroll
      for (int j = 0; j < 4; ++j)
        acc[i][j] = __builtin_amdgcn_mfma_f32_16x16x32_bf16(af[i], bf[j], acc[i][j], 0, 0, 0);
    __builtin_amdgcn_s_setprio(0);
    // counted wait: tile kt+1 landed, tiles kt+2/kt+3 (8 loads) stay in flight
    if (kt < 29)       asm volatile("s_waitcnt vmcnt(8)" ::: "memory");
    else if (kt == 29) asm volatile("s_waitcnt vmcnt(4)" ::: "memory");
    else if (kt == 30) asm volatile("s_waitcnt vmcnt(0)" ::: "memory");
    if (kt < 31) {
      __builtin_amdgcn_s_barrier();
      asm volatile("" ::: "memory");  // fence: next iter's ds_reads must not hoist above
    }
  }
#undef STG

  if (MODE == 0) {
    const size_t G = 67108864;  // elements per q/k/v plane
    const int g = tn >> 10;     // 0:q 1:k 2:v (256 | 1024 -> uniform per block)
    const float* bias = (g == 0) ? b0 : (g == 1) ? b1 : b2;
    const int nn0 = (tn & 1023) + wc * 64;
#pragma unroll
    for (int j = 0; j < 4; ++j) {
      const int nn = nn0 + j * 16 + lo;
      const float bv = bias[nn];
      const int h = nn >> 5, hd = nn & 31;
      if (g < 2) {
#pragma unroll
        for (int i = 0; i < 8; ++i) {
          const int m0 = tm + wr * 128 + i * 16 + hi * 4;  // row = (l>>4)*4 + reg
          const int b = m0 >> 6, s0 = m0 & 63;
          const size_t base = (size_t)g * G + ((size_t)(b * 32 + h) * 64 + s0) * 32 + hd;
#pragma unroll
          for (int r = 0; r < 4; ++r) oq[base + (size_t)r * 32] = f2b(acc[i][j][r] + bv);
        }
      } else {
#pragma unroll
        for (int i = 0; i < 8; ++i) {
          const int m0 = tm + wr * 128 + i * 16 + hi * 4;
          const int b = m0 >> 6, s0 = m0 & 63;
          ushort4 pk;
          pk.x = f2b(acc[i][j][0] + bv);
          pk.y = f2b(acc[i][j][1] + bv);
          pk.z = f2b(acc[i][j][2] + bv);
          pk.w = f2b(acc[i][j][3] + bv);
          *(ushort4*)(oq + 2 * G + ((size_t)(b * 32 + h) * 32 + hd) * 64 + s0) = pk;
        }
      }
    }
  } else {
#pragma unroll
    for (int j = 0; j < 4; ++j) {
      const int n = tn + wc * 64 + j * 16 + lo;
      const float bv = b0[n];
#pragma unroll
      for (int i = 0; i < 8; ++i) {
        const int m0 = tm + wr * 128 + i * 16 + hi * 4;
#pragma unroll
        for (int r = 0; r < 4; ++r) of[(size_t)(m0 + r) * 1024 + n] = acc[i][j][r] + bv;
      }
    }
  }
}

// ---------------- attention: one (b,h) per 256-thread block, wave w owns q-rows [w*16, w*16+16) --
__global__ __launch_bounds__(256) void k_attn(
    const u16* __restrict__ qkv, const u16* __restrict__ rq,
    const u16* __restrict__ rk, u16* __restrict__ att) {
  __shared__ alignas(16) u16 buf[64 * 244];  // Bq then Bk boards (bf16), rows padded to 244
  __shared__ alignas(16) u16 pl[64 * 72];    // P (exp scores) bf16, padded rows
  const int l = threadIdx.x & 63, w = threadIdx.x >> 6;
  const int lo = l & 15, hi = l >> 4;
  const int b = blockIdx.x, h = blockIdx.y;
  const size_t G = 67108864;
  const u16* qp = qkv + (size_t)(b * 32 + h) * 2048;          // [64][32]
  const u16* kp = qkv + G + (size_t)(b * 32 + h) * 2048;      // [64][32]
  const u16* vp = qkv + 2 * G + (size_t)(b * 32 + h) * 2048;  // V^T [32][64]

  // Q fragment (A-operand): rows w*16+lo, d = hi*8..+8
  b16x8 qf = *(const b16x8*)(qp + (w * 16 + lo) * 32 + hi * 8);

  // Phase 1: QK^T  (B-operand: lane holds K[kt*16+lo][d contiguous])
  f32x4 s0[4];
#pragma unroll
  for (int kt = 0; kt < 4; ++kt) {
    b16x8 kf = *(const b16x8*)(kp + (kt * 16 + lo) * 32 + hi * 8);
    f32x4 z = (f32x4){0.f, 0.f, 0.f, 0.f};
    s0[kt] = __builtin_amdgcn_mfma_f32_16x16x32_bf16(qf, kf, z, 0, 0, 0);
  }

  // Phase 2: Bq = Q @ Rq[h]^T -> buf rows w*16.. (wave-private)
  const u16* rqh = rq + (size_t)h * 7680;  // 240*32
#pragma unroll
  for (int nt = 0; nt < 15; ++nt) {
    b16x8 rf = *(const b16x8*)(rqh + (nt * 16 + lo) * 32 + hi * 8);
    f32x4 z = (f32x4){0.f, 0.f, 0.f, 0.f};
    f32x4 c = __builtin_amdgcn_mfma_f32_16x16x32_bf16(qf, rf, z, 0, 0, 0);
#pragma unroll
    for (int r = 0; r < 4; ++r) buf[(w * 16 + hi * 4 + r) * 244 + nt * 16 + lo] = f2b(c[r]);
  }
  // Phase 3: gather Bq (reads only this wave's rows; same-wave LDS RAW -> lgkmcnt)
#pragma unroll
  for (int kt = 0; kt < 4; ++kt)
#pragma unroll
    for (int r = 0; r < 4; ++r) {
      int q = w * 16 + hi * 4 + r, k = kt * 16 + lo;
      int rel = 15 * ((q >> 3) - (k >> 3) + 7) + (q & 7) - (k & 7) + 7;
      s0[kt][r] += b2f(buf[q * 244 + rel]);
    }

  // Phase 4: Bk = K @ Rk[h]^T -> buf rows w*16.. (overwrites own rows only)
  b16x8 kfa = *(const b16x8*)(kp + (w * 16 + lo) * 32 + hi * 8);
  const u16* rkh = rk + (size_t)h * 7680;
#pragma unroll
  for (int nt = 0; nt < 15; ++nt) {
    b16x8 rf = *(const b16x8*)(rkh + (nt * 16 + lo) * 32 + hi * 8);
    f32x4 z = (f32x4){0.f, 0.f, 0.f, 0.f};
    f32x4 c = __builtin_amdgcn_mfma_f32_16x16x32_bf16(kfa, rf, z, 0, 0, 0);
#pragma unroll
    for (int r = 0; r < 4; ++r) buf[(w * 16 + hi * 4 + r) * 244 + nt * 16 + lo] = f2b(c[r]);
  }
  __syncthreads();  // Bk board read cross-wave below
  // Phase 5: gather Bk (indexed by k row -> all rows)
#pragma unroll
  for (int kt = 0; kt < 4; ++kt)
#pragma unroll
    for (int r = 0; r < 4; ++r) {
      int q = w * 16 + hi * 4 + r, k = kt * 16 + lo;
      int rel = 15 * ((q >> 3) - (k >> 3) + 7) + (q & 7) - (k & 7) + 7;
      s0[kt][r] += b2f(buf[k * 244 + rel]);
    }

  // Phase 6: scale + softmax (rows live in 16-lane groups; reduce over xor 1,2,4,8)
  const float sc = 0.17677669529663689f;  // 1/sqrt(32)
#pragma unroll
  for (int kt = 0; kt < 4; ++kt) s0[kt] *= sc;
  float p[4][4], rsum[4];
#pragma unroll
  for (int r = 0; r < 4; ++r) {
    float m = s0[0][r];
    m = fmaxf(m, s0[1][r]); m = fmaxf(m, s0[2][r]); m = fmaxf(m, s0[3][r]);
    m = fmaxf(m, __shfl_xor(m, 1));
    m = fmaxf(m, __shfl_xor(m, 2));
    m = fmaxf(m, __shfl_xor(m, 4));
    m = fmaxf(m, __shfl_xor(m, 8));
    float sum = 0.f;
#pragma unroll
    for (int kt = 0; kt < 4; ++kt) {
      float e = __expf(s0[kt][r] - m);
      p[kt][r] = e;
      sum += e;
    }
    sum += __shfl_xor(sum, 1);
    sum += __shfl_xor(sum, 2);
    sum += __shfl_xor(sum, 4);
    sum += __shfl_xor(sum, 8);
    rsum[r] = 1.f / sum;
  }

  // Phase 7: P -> LDS (wave-private rows; normalization deferred to output)
#pragma unroll
  for (int kt = 0; kt < 4; ++kt)
#pragma unroll
    for (int r = 0; r < 4; ++r) pl[(w * 16 + hi * 4 + r) * 72 + kt * 16 + lo] = f2b(p[kt][r]);

  // Phase 8: O = P @ V   (A: P rows w*16+lo; B: V^T rows hd, k contiguous)
  f32x4 o0 = (f32x4){0.f, 0.f, 0.f, 0.f}, o1 = (f32x4){0.f, 0.f, 0.f, 0.f};
#pragma unroll
  for (int ks = 0; ks < 2; ++ks) {
    b16x8 pa = *(const b16x8*)(pl + (w * 16 + lo) * 72 + ks * 32 + hi * 8);
    b16x8 v0 = *(const b16x8*)(vp + lo * 64 + ks * 32 + hi * 8);
    b16x8 v1 = *(const b16x8*)(vp + (16 + lo) * 64 + ks * 32 + hi * 8);
    o0 = __builtin_amdgcn_mfma_f32_16x16x32_bf16(pa, v0, o0, 0, 0, 0);
    o1 = __builtin_amdgcn_mfma_f32_16x16x32_bf16(pa, v1, o1, 0, 0, 0);
  }

  // Phase 9: write att[b][s][h*32+hd] (bf16), scaled by 1/rowsum
#pragma unroll
  for (int r = 0; r < 4; ++r) {
    int q = w * 16 + hi * 4 + r;
    size_t base = (size_t)(b * 64 + q) * 1024 + h * 32;
    att[base + lo] = f2b(o0[r] * rsum[r]);
    att[base + 16 + lo] = f2b(o1[r] * rsum[r]);
  }
}

extern "C" void kernel_launch(void* const* d_in, const int* in_sizes, int n_in,
                              void* d_out, int out_size, void* d_ws, size_t ws_size,
                              hipStream_t stream) {
  const float* x   = (const float*)d_in[0];
  const float* qw  = (const float*)d_in[1];
  const float* qb  = (const float*)d_in[2];
  const float* kw  = (const float*)d_in[3];
  const float* kb  = (const float*)d_in[4];
  const float* vw  = (const float*)d_in[5];
  const float* vb  = (const float*)d_in[6];
  const float* ow  = (const float*)d_in[7];
  const float* ob  = (const float*)d_in[8];
  const float* rqw = (const float*)d_in[9];
  const float* rkw = (const float*)d_in[10];

  // workspace layout (total 680,460,288 bytes)
  if (ws_size < 680460288ULL) return;  // diagnostic: leaves d_out zeroed -> absmax == max|ref|
  char* p = (char*)d_ws;
  u16* ws_x   = (u16*)p; p += (size_t)65536 * 1024 * 2;      // x bf16
  u16* ws_w   = (u16*)p; p += (size_t)3 * 1024 * 1024 * 2;   // qkv weights bf16 [3072][1024]
  u16* ws_wo  = (u16*)p; p += (size_t)1024 * 1024 * 2;       // out_w bf16
  u16* ws_rq  = (u16*)p; p += (size_t)32 * 240 * 32 * 2;     // Rq [h][r][d]
  u16* ws_rk  = (u16*)p; p += (size_t)32 * 240 * 32 * 2;     // Rk [h][r][d]
  u16* ws_qkv = (u16*)p; p += (size_t)3 * 67108864 * 2;      // q,k [b][h][s][hd]; v [b][h][hd][s]
  u16* ws_att = (u16*)p; p += (size_t)65536 * 1024 * 2;      // attention out [b*s][1024]

  k_cvt<<<32768, 256, 0, stream>>>(x, ws_x, 67108864L);
  k_cvt<<<512, 256, 0, stream>>>(qw, ws_w, 1048576L);
  k_cvt<<<512, 256, 0, stream>>>(kw, ws_w + 1048576, 1048576L);
  k_cvt<<<512, 256, 0, stream>>>(vw, ws_w + 2097152, 1048576L);
  k_cvt<<<512, 256, 0, stream>>>(ow, ws_wo, 1048576L);
  k_rpe<<<dim3(30, 32, 2), 256, 0, stream>>>(rqw, rkw, ws_rq, ws_rk);

  // QKV projection: 12 n-tiles x 256 m-tiles (nwg=3072, %8==0 for XCD swizzle)
  k_gemm<0><<<dim3(12, 256), 512, 0, stream>>>(ws_x, ws_w, qb, kb, vb, ws_qkv, nullptr);
  // attention: grid.x = b (fastest) so consecutive blocks reuse Rq[h]/Rk[h] in cache
  k_attn<<<dim3(1024, 32), 256, 0, stream>>>(ws_qkv, ws_rq, ws_rk, ws_att);
  // output projection: 4 n-tiles x 256 m-tiles (nwg=1024)
  k_gemm<1><<<dim3(4, 256), 512, 0, stream>>>(ws_att, ws_wo, ob, nullptr, nullptr, nullptr,
                                              (float*)d_out);
}

// Round 4
// 1019.638 us; speedup vs baseline: 1.4246x; 1.0140x over previous
//
#include <hip/hip_runtime.h>
#include <hip/hip_bf16.h>

#define AS1 __attribute__((address_space(1)))
#define AS3 __attribute__((address_space(3)))

typedef __attribute__((ext_vector_type(4))) float f32x4;
typedef __attribute__((ext_vector_type(8))) short b16x8;     // 8 bf16 (4 VGPRs) MFMA operand
typedef __attribute__((ext_vector_type(8))) unsigned short u16x8;
typedef unsigned short u16;

static __device__ __forceinline__ u16 f2b(float f) {
  return __builtin_bit_cast(u16, __float2bfloat16(f));
}
static __device__ __forceinline__ float b2f(u16 u) {
  unsigned v = ((unsigned)u) << 16;
  return __builtin_bit_cast(float, v);
}
static __device__ __forceinline__ void gl2lds16(const u16* g, u16* l) {
  __builtin_amdgcn_global_load_lds((const AS1 void*)g, (AS3 void*)l, 16, 0, 0);
}

// ---------------- fp32 -> bf16 convert, 8 elems/thread ----------------
__global__ void k_cvt(const float* __restrict__ s, u16* __restrict__ d, long n) {
  long i = ((long)blockIdx.x * 256 + threadIdx.x) * 8;
  if (i >= n) return;
  float4 a = *(const float4*)(s + i);
  float4 b = *(const float4*)(s + i + 4);
  u16x8 o;
  o[0] = f2b(a.x); o[1] = f2b(a.y); o[2] = f2b(a.z); o[3] = f2b(a.w);
  o[4] = f2b(b.x); o[5] = f2b(b.y); o[6] = f2b(b.z); o[7] = f2b(b.w);
  *(u16x8*)(d + i) = o;
}

// ------- RPE tables: out[h][r(240)][d(32)] = bf16(src[(d*32+h)*225 + r]), r>=225 -> 0 -------
__global__ void k_rpe(const float* __restrict__ rq, const float* __restrict__ rk,
                      u16* __restrict__ oq, u16* __restrict__ ok) {
  int h = blockIdx.y;
  int r = blockIdx.x * 8 + (threadIdx.x >> 5);
  int d = threadIdx.x & 31;
  const float* s = blockIdx.z ? rk : rq;
  u16* o = blockIdx.z ? ok : oq;
  float v = (r < 225) ? s[(d * 32 + h) * 225 + r] : 0.f;
  o[(h * 240 + r) * 32 + d] = f2b(v);
}

// ---------------- 256x256 tile GEMM, BK=32, 4-deep pipeline + register prefetch ----------------
// A[M][1024] bf16 (k contiguous), Bw[N][1024] bf16 (n-major, k contiguous).
// 512 threads = 8 waves (2M x 4N); per-wave output 128x64.
// LDS: 4 circular buffers x (A 256x32 + B 256x32) bf16 = 128 KiB.
// XOR swizzle (both sides, rule 21): staging pre-swizzles the GLOBAL source per lane
// (LDS dest linear); reads apply the same involution -> measured 0 bank conflicts.
// Double register set (cur/nxt): step kt prefetches buf[kt+1] fragments into nxt BEFORE the
// MFMA burst on cur; compiler emits counted lgkmcnt so 12 ds_read_b128 overlap 32 MFMAs.
// vmcnt LEDGER (R4 fix: prologue vmcnt(4), was vmcnt(8) -> tile-1 read race):
//   prologue: STG 0,1,2 (12 out) -> vmcnt(4): tiles 0,1 landed, 2 in flight.
//   invariant at step kt top: tiles <= kt+1 landed, kt+2 in flight.
//   STG(kt+3) [8 out]; RDF(kt+1) ok; MMS(kt); vmcnt(4)+bar -> kt+2 landed, kt+3 in flight;
//   STG(kt+4) [8 out]; RDF(kt+2) ok; MMS(kt+1); vmcnt(4)+bar -> invariant(kt+2). WAR: each
//   STG's target buffer was consumed before the barrier one step earlier.
// MODE 0: qkv epilogue -> per-head layout (+bias, V transposed). MODE 1: fp32 out + bias.
template <int MODE>
__global__ __launch_bounds__(512) void k_gemm(
    const u16* __restrict__ A, const u16* __restrict__ Bw,
    const float* __restrict__ b0, const float* __restrict__ b1, const float* __restrict__ b2,
    u16* __restrict__ oq, float* __restrict__ of) {
  __shared__ alignas(16) u16 lds[4][16384];  // [buf][A:0..8191 | B:8192..16383]
  const int tid = threadIdx.x;
  const int l = tid & 63, w = tid >> 6;
  const int lo = l & 15, hi = l >> 4;
  const int wr = w >> 2, wc = w & 3;

  // bijective XCD swizzle (nwg % 8 == 0 for both grids)
  const int nbx = gridDim.x;
  const int nb = nbx * gridDim.y;
  const int bid = blockIdx.y * nbx + blockIdx.x;
  const int ord = (bid & 7) * (nb >> 3) + (bid >> 3);
  const int tn = (ord % nbx) * 256, tm = (ord / nbx) * 256;

  // staging lane map: pre-swizzled global source, linear LDS dest (lane*16B)
  const int sl = (tid & 7) ^ ((tid >> 3) & 7);   // logical slot this lane's dest holds
  const int srow = 2 * (tid >> 3) + (sl >> 2);   // row within half-tile (q=0); q=1 adds 128
  const int scol = (sl & 3) * 8;
  const u16* gA = A + (size_t)(tm + srow) * 1024 + scol;
  const u16* gB = Bw + (size_t)(tn + srow) * 1024 + scol;
  u16* dst = &lds[0][0] + tid * 8;

  // fragment-read lane constants (same involution)
  const int p7 = (lo >> 1) & 7;
  const int slr = ((lo & 1) * 4 + hi) ^ p7;
  const int aoff = wr * 4096 + (lo >> 1) * 64 + slr * 8;
  const int boff = 8192 + wc * 2048 + (lo >> 1) * 64 + slr * 8;

  f32x4 acc[8][4];
#pragma unroll
  for (int i = 0; i < 8; ++i)
#pragma unroll
    for (int j = 0; j < 4; ++j) acc[i][j] = (f32x4){0.f, 0.f, 0.f, 0.f};

#define STG(t) { const int kc = (t) * 32; u16* d = dst + ((t) & 3) * 16384; \
    gl2lds16(gA + kc, d);           gl2lds16(gA + 131072 + kc, d + 4096); \
    gl2lds16(gB + kc, d + 8192);    gl2lds16(gB + 131072 + kc, d + 12288); }
#define RDF(fa, fb, bi) { const u16* _b = &lds[0][0] + (bi) * 16384; \
    _Pragma("unroll") for (int _i = 0; _i < 8; ++_i) fa[_i] = *(const b16x8*)(_b + aoff + _i * 512); \
    _Pragma("unroll") for (int _j = 0; _j < 4; ++_j) fb[_j] = *(const b16x8*)(_b + boff + _j * 512); }
#define MMS(fa, fb) { __builtin_amdgcn_s_setprio(1); \
    _Pragma("unroll") for (int _i = 0; _i < 8; ++_i) \
    _Pragma("unroll") for (int _j = 0; _j < 4; ++_j) \
      acc[_i][_j] = __builtin_amdgcn_mfma_f32_16x16x32_bf16(fa[_i], fb[_j], acc[_i][_j], 0, 0, 0); \
    __builtin_amdgcn_s_setprio(0); }
#define WB(n) { asm volatile("s_waitcnt vmcnt(" #n ")" ::: "memory"); \
    __builtin_amdgcn_s_barrier(); asm volatile("" ::: "memory"); }

  b16x8 fa0[8], fb0[4], fa1[8], fb1[4];

  STG(0) STG(1) STG(2)
  WB(4)               // tiles 0,1 landed (all waves after barrier); 2 in flight
  RDF(fa0, fb0, 0)

  for (int kt = 0; kt < 28; kt += 2) {
    STG(kt + 3)
    RDF(fa1, fb1, (kt + 1) & 3)   // tile kt+1 landed per invariant
    MMS(fa0, fb0)                 // tile kt (compiler inserts counted lgkm)
    WB(4)                         // tile kt+2 landed; kt+3 in flight
    STG(kt + 4)
    RDF(fa0, fb0, (kt + 2) & 3)
    MMS(fa1, fb1)                 // tile kt+1
    WB(4)                         // tile kt+3 landed; kt+4 in flight
  }
  // tail: kt = 28..31 (tiles 0..31, 32 total); entry: tiles <=29 landed, 30 in flight
  STG(31)
  RDF(fa1, fb1, 1)    // tile 29
  MMS(fa0, fb0)       // tile 28
  WB(4)               // tile 30 landed; 31 in flight
  RDF(fa0, fb0, 2)    // tile 30
  MMS(fa1, fb1)       // tile 29
  WB(0)               // tile 31 landed
  RDF(fa1, fb1, 3)    // tile 31
  MMS(fa0, fb0)       // tile 30
  MMS(fa1, fb1)       // tile 31
#undef STG
#undef RDF
#undef MMS
#undef WB

  if (MODE == 0) {
    const size_t G = 67108864;  // elements per q/k/v plane
    const int g = tn >> 10;     // 0:q 1:k 2:v (256 | 1024 -> uniform per block)
    const float* bias = (g == 0) ? b0 : (g == 1) ? b1 : b2;
    const int nn0 = (tn & 1023) + wc * 64;
#pragma unroll
    for (int j = 0; j < 4; ++j) {
      const int nn = nn0 + j * 16 + lo;
      const float bv = bias[nn];
      const int h = nn >> 5, hd = nn & 31;
      if (g < 2) {
#pragma unroll
        for (int i = 0; i < 8; ++i) {
          const int m0 = tm + wr * 128 + i * 16 + hi * 4;  // row = (l>>4)*4 + reg
          const int b = m0 >> 6, s0 = m0 & 63;
          const size_t base = (size_t)g * G + ((size_t)(b * 32 + h) * 64 + s0) * 32 + hd;
#pragma unroll
          for (int r = 0; r < 4; ++r) oq[base + (size_t)r * 32] = f2b(acc[i][j][r] + bv);
        }
      } else {
#pragma unroll
        for (int i = 0; i < 8; ++i) {
          const int m0 = tm + wr * 128 + i * 16 + hi * 4;
          const int b = m0 >> 6, s0 = m0 & 63;
          ushort4 pk;
          pk.x = f2b(acc[i][j][0] + bv);
          pk.y = f2b(acc[i][j][1] + bv);
          pk.z = f2b(acc[i][j][2] + bv);
          pk.w = f2b(acc[i][j][3] + bv);
          *(ushort4*)(oq + 2 * G + ((size_t)(b * 32 + h) * 32 + hd) * 64 + s0) = pk;
        }
      }
    }
  } else {
#pragma unroll
    for (int j = 0; j < 4; ++j) {
      const int n = tn + wc * 64 + j * 16 + lo;
      const float bv = b0[n];
#pragma unroll
      for (int i = 0; i < 8; ++i) {
        const int m0 = tm + wr * 128 + i * 16 + hi * 4;
#pragma unroll
        for (int r = 0; r < 4; ++r) of[(size_t)(m0 + r) * 1024 + n] = acc[i][j][r] + bv;
      }
    }
  }
}

// ---------------- attention: one (b,h) per 256-thread block, wave w owns q-rows [w*16, w*16+16) --
// Board layout [q>>2][col(240)][q&3] u16: MFMA tile stores become ONE ds_write_b64 (4 rows,
// same col) instead of 4 scalar stores. pl (P matrix) overlays board (extra barrier). V hoisted.
__global__ __launch_bounds__(256) void k_attn(
    const u16* __restrict__ qkv, const u16* __restrict__ rq,
    const u16* __restrict__ rk, u16* __restrict__ att) {
  __shared__ alignas(16) u16 board[16 * 240 * 4];  // 30720 B; pl overlays first 9216 B
  u16* pl = board;                                 // [64][72] row-major
  const int l = threadIdx.x & 63, w = threadIdx.x >> 6;
  const int lo = l & 15, hi = l >> 4;
  const int b = blockIdx.x, h = blockIdx.y;
  const size_t G = 67108864;
  const u16* qp = qkv + (size_t)(b * 32 + h) * 2048;          // [64][32]
  const u16* kp = qkv + G + (size_t)(b * 32 + h) * 2048;      // [64][32]
  const u16* vp = qkv + 2 * G + (size_t)(b * 32 + h) * 2048;  // V^T [32][64]

  // Q fragment (A-operand): rows w*16+lo, d = hi*8..+8
  b16x8 qf = *(const b16x8*)(qp + (w * 16 + lo) * 32 + hi * 8);
  // hoisted V fragments (used phase 8; HBM latency hides under board GEMMs)
  b16x8 v00 = *(const b16x8*)(vp + lo * 64 + hi * 8);
  b16x8 v01 = *(const b16x8*)(vp + lo * 64 + 32 + hi * 8);
  b16x8 v10 = *(const b16x8*)(vp + (16 + lo) * 64 + hi * 8);
  b16x8 v11 = *(const b16x8*)(vp + (16 + lo) * 64 + 32 + hi * 8);

  // Phase 1: QK^T  (B-operand: lane holds K[kt*16+lo][d contiguous])
  f32x4 s0[4];
#pragma unroll
  for (int kt = 0; kt < 4; ++kt) {
    b16x8 kf = *(const b16x8*)(kp + (kt * 16 + lo) * 32 + hi * 8);
    f32x4 z = (f32x4){0.f, 0.f, 0.f, 0.f};
    s0[kt] = __builtin_amdgcn_mfma_f32_16x16x32_bf16(qf, kf, z, 0, 0, 0);
  }

  // Phase 2: Bq = Q @ Rq[h]^T -> board rows (w*4+hi), packed b64 stores (wave-private rows)
  const u16* rqh = rq + (size_t)h * 7680;  // 240*32
#pragma unroll
  for (int nt = 0; nt < 15; ++nt) {
    b16x8 rf = *(const b16x8*)(rqh + (nt * 16 + lo) * 32 + hi * 8);
    f32x4 z = (f32x4){0.f, 0.f, 0.f, 0.f};
    f32x4 c = __builtin_amdgcn_mfma_f32_16x16x32_bf16(qf, rf, z, 0, 0, 0);
    ushort4 pk;
    pk.x = f2b(c[0]); pk.y = f2b(c[1]); pk.z = f2b(c[2]); pk.w = f2b(c[3]);
    *(ushort4*)(board + (((w * 4 + hi) * 240 + nt * 16 + lo) << 2)) = pk;
  }
  // Phase 3: gather Bq (reads only this wave's rows; same-wave LDS RAW -> lgkmcnt)
#pragma unroll
  for (int kt = 0; kt < 4; ++kt)
#pragma unroll
    for (int r = 0; r < 4; ++r) {
      int q = w * 16 + hi * 4 + r, k = kt * 16 + lo;
      int rel = 15 * ((q >> 3) - (k >> 3) + 7) + (q & 7) - (k & 7) + 7;
      s0[kt][r] += b2f(board[((w * 4 + hi) * 240 + rel) * 4 + r]);
    }

  // Phase 4: Bk = K @ Rk[h]^T -> board rows (w*4+hi) (overwrites own rows only)
  b16x8 kfa = *(const b16x8*)(kp + (w * 16 + lo) * 32 + hi * 8);
  const u16* rkh = rk + (size_t)h * 7680;
#pragma unroll
  for (int nt = 0; nt < 15; ++nt) {
    b16x8 rf = *(const b16x8*)(rkh + (nt * 16 + lo) * 32 + hi * 8);
    f32x4 z = (f32x4){0.f, 0.f, 0.f, 0.f};
    f32x4 c = __builtin_amdgcn_mfma_f32_16x16x32_bf16(kfa, rf, z, 0, 0, 0);
    ushort4 pk;
    pk.x = f2b(c[0]); pk.y = f2b(c[1]); pk.z = f2b(c[2]); pk.w = f2b(c[3]);
    *(ushort4*)(board + (((w * 4 + hi) * 240 + nt * 16 + lo) << 2)) = pk;
  }
  __syncthreads();  // Bk board read cross-wave below
  // Phase 5: gather Bk (indexed by k row -> all rows)
#pragma unroll
  for (int kt = 0; kt < 4; ++kt)
#pragma unroll
    for (int r = 0; r < 4; ++r) {
      int q = w * 16 + hi * 4 + r, k = kt * 16 + lo;
      int rel = 15 * ((q >> 3) - (k >> 3) + 7) + (q & 7) - (k & 7) + 7;
      s0[kt][r] += b2f(board[((k >> 2) * 240 + rel) * 4 + (k & 3)]);
    }

  // Phase 6: scale + softmax (rows live in 16-lane groups; reduce over xor 1,2,4,8)
  const float sc = 0.17677669529663689f;  // 1/sqrt(32)
#pragma unroll
  for (int kt = 0; kt < 4; ++kt) s0[kt] *= sc;
  float p[4][4], rsum[4];
#pragma unroll
  for (int r = 0; r < 4; ++r) {
    float m = s0[0][r];
    m = fmaxf(m, s0[1][r]); m = fmaxf(m, s0[2][r]); m = fmaxf(m, s0[3][r]);
    m = fmaxf(m, __shfl_xor(m, 1));
    m = fmaxf(m, __shfl_xor(m, 2));
    m = fmaxf(m, __shfl_xor(m, 4));
    m = fmaxf(m, __shfl_xor(m, 8));
    float sum = 0.f;
#pragma unroll
    for (int kt = 0; kt < 4; ++kt) {
      float e = __expf(s0[kt][r] - m);
      p[kt][r] = e;
      sum += e;
    }
    sum += __shfl_xor(sum, 1);
    sum += __shfl_xor(sum, 2);
    sum += __shfl_xor(sum, 4);
    sum += __shfl_xor(sum, 8);
    rsum[r] = 1.f / sum;
  }

  __syncthreads();  // overlay guard: all board gathers done before pl overwrites board bytes

  // Phase 7: P -> LDS (wave-private rows; normalization deferred to output)
#pragma unroll
  for (int kt = 0; kt < 4; ++kt)
#pragma unroll
    for (int r = 0; r < 4; ++r) pl[(w * 16 + hi * 4 + r) * 72 + kt * 16 + lo] = f2b(p[kt][r]);

  // Phase 8: O = P @ V   (A: P rows w*16+lo; B: V^T rows hd, k contiguous)
  f32x4 o0 = (f32x4){0.f, 0.f, 0.f, 0.f}, o1 = (f32x4){0.f, 0.f, 0.f, 0.f};
  {
    b16x8 pa0 = *(const b16x8*)(pl + (w * 16 + lo) * 72 + hi * 8);
    b16x8 pa1 = *(const b16x8*)(pl + (w * 16 + lo) * 72 + 32 + hi * 8);
    o0 = __builtin_amdgcn_mfma_f32_16x16x32_bf16(pa0, v00, o0, 0, 0, 0);
    o1 = __builtin_amdgcn_mfma_f32_16x16x32_bf16(pa0, v10, o1, 0, 0, 0);
    o0 = __builtin_amdgcn_mfma_f32_16x16x32_bf16(pa1, v01, o0, 0, 0, 0);
    o1 = __builtin_amdgcn_mfma_f32_16x16x32_bf16(pa1, v11, o1, 0, 0, 0);
  }

  // Phase 9: write att[b][s][h*32+hd] (bf16), scaled by 1/rowsum
#pragma unroll
  for (int r = 0; r < 4; ++r) {
    int q = w * 16 + hi * 4 + r;
    size_t base = (size_t)(b * 64 + q) * 1024 + h * 32;
    att[base + lo] = f2b(o0[r] * rsum[r]);
    att[base + 16 + lo] = f2b(o1[r] * rsum[r]);
  }
}

extern "C" void kernel_launch(void* const* d_in, const int* in_sizes, int n_in,
                              void* d_out, int out_size, void* d_ws, size_t ws_size,
                              hipStream_t stream) {
  const float* x   = (const float*)d_in[0];
  const float* qw  = (const float*)d_in[1];
  const float* qb  = (const float*)d_in[2];
  const float* kw  = (const float*)d_in[3];
  const float* kb  = (const float*)d_in[4];
  const float* vw  = (const float*)d_in[5];
  const float* vb  = (const float*)d_in[6];
  const float* ow  = (const float*)d_in[7];
  const float* ob  = (const float*)d_in[8];
  const float* rqw = (const float*)d_in[9];
  const float* rkw = (const float*)d_in[10];

  // workspace layout (total 680,460,288 bytes)
  if (ws_size < 680460288ULL) return;  // diagnostic: leaves d_out zeroed -> absmax == max|ref|
  char* p = (char*)d_ws;
  u16* ws_x   = (u16*)p; p += (size_t)65536 * 1024 * 2;      // x bf16
  u16* ws_w   = (u16*)p; p += (size_t)3 * 1024 * 1024 * 2;   // qkv weights bf16 [3072][1024]
  u16* ws_wo  = (u16*)p; p += (size_t)1024 * 1024 * 2;       // out_w bf16
  u16* ws_rq  = (u16*)p; p += (size_t)32 * 240 * 32 * 2;     // Rq [h][r][d]
  u16* ws_rk  = (u16*)p; p += (size_t)32 * 240 * 32 * 2;     // Rk [h][r][d]
  u16* ws_qkv = (u16*)p; p += (size_t)3 * 67108864 * 2;      // q,k [b][h][s][hd]; v [b][h][hd][s]
  u16* ws_att = (u16*)p; p += (size_t)65536 * 1024 * 2;      // attention out [b*s][1024]

  k_cvt<<<32768, 256, 0, stream>>>(x, ws_x, 67108864L);
  k_cvt<<<512, 256, 0, stream>>>(qw, ws_w, 1048576L);
  k_cvt<<<512, 256, 0, stream>>>(kw, ws_w + 1048576, 1048576L);
  k_cvt<<<512, 256, 0, stream>>>(vw, ws_w + 2097152, 1048576L);
  k_cvt<<<512, 256, 0, stream>>>(ow, ws_wo, 1048576L);
  k_rpe<<<dim3(30, 32, 2), 256, 0, stream>>>(rqw, rkw, ws_rq, ws_rk);

  // QKV projection: 12 n-tiles x 256 m-tiles (nwg=3072, %8==0 for XCD swizzle)
  k_gemm<0><<<dim3(12, 256), 512, 0, stream>>>(ws_x, ws_w, qb, kb, vb, ws_qkv, nullptr);
  // attention: grid.x = b (fastest) so consecutive blocks reuse Rq[h]/Rk[h] in cache
  k_attn<<<dim3(1024, 32), 256, 0, stream>>>(ws_qkv, ws_rq, ws_rk, ws_att);
  // output projection: 4 n-tiles x 256 m-tiles (nwg=1024)
  k_gemm<1><<<dim3(4, 256), 512, 0, stream>>>(ws_att, ws_wo, ob, nullptr, nullptr, nullptr,
                                              (float*)d_out);
}

// Round 5
// 1008.504 us; speedup vs baseline: 1.4403x; 1.0110x over previous
//
#include <hip/hip_runtime.h>
#include <hip/hip_bf16.h>

#define AS1 __attribute__((address_space(1)))
#define AS3 __attribute__((address_space(3)))

typedef __attribute__((ext_vector_type(4))) float f32x4;
typedef __attribute__((ext_vector_type(8))) short b16x8;     // 8 bf16 (4 VGPRs) MFMA operand
typedef __attribute__((ext_vector_type(8))) unsigned short u16x8;
typedef unsigned short u16;

static __device__ __forceinline__ u16 f2b(float f) {
  return __builtin_bit_cast(u16, __float2bfloat16(f));
}
static __device__ __forceinline__ float b2f(u16 u) {
  unsigned v = ((unsigned)u) << 16;
  return __builtin_bit_cast(float, v);
}
static __device__ __forceinline__ void gl2lds16(const u16* g, u16* l) {
  __builtin_amdgcn_global_load_lds((const AS1 void*)g, (AS3 void*)l, 16, 0, 0);
}

// ---------------- fp32 -> bf16 convert, 8 elems/thread ----------------
__global__ void k_cvt(const float* __restrict__ s, u16* __restrict__ d, long n) {
  long i = ((long)blockIdx.x * 256 + threadIdx.x) * 8;
  if (i >= n) return;
  float4 a = *(const float4*)(s + i);
  float4 b = *(const float4*)(s + i + 4);
  u16x8 o;
  o[0] = f2b(a.x); o[1] = f2b(a.y); o[2] = f2b(a.z); o[3] = f2b(a.w);
  o[4] = f2b(b.x); o[5] = f2b(b.y); o[6] = f2b(b.z); o[7] = f2b(b.w);
  *(u16x8*)(d + i) = o;
}

// ------- RPE tables: out[h][r(240)][d(32)] = bf16(src[(d*32+h)*225 + r]), r>=225 -> 0 -------
__global__ void k_rpe(const float* __restrict__ rq, const float* __restrict__ rk,
                      u16* __restrict__ oq, u16* __restrict__ ok) {
  int h = blockIdx.y;
  int r = blockIdx.x * 8 + (threadIdx.x >> 5);
  int d = threadIdx.x & 31;
  const float* s = blockIdx.z ? rk : rq;
  u16* o = blockIdx.z ? ok : oq;
  float v = (r < 225) ? s[(d * 32 + h) * 225 + r] : 0.f;
  o[(h * 240 + r) * 32 + d] = f2b(v);
}

// ------- 256x256 tile GEMM, BK=32, 4-deep counted-vmcnt pipeline, 2-phase K-step (m201-style) ----
// A[M][1024] bf16 (k contiguous), Bw[N][1024] bf16 (n-major, k contiguous).
// 512 threads = 8 waves (2M x 4N); per-wave output 128x64.
// LDS: 4 circular buffers x (A 256x32 + B 256x32) bf16 = 128 KiB.
// XOR swizzle (both sides): staging pre-swizzles the GLOBAL source per lane (LDS dest linear);
// reads apply the same involution -> measured 0 bank conflicts.
// R5: K-step split into 2 phases of 16 MFMA each with per-phase {stage || ds_read -> barrier ->
// lgkmcnt(0) -> setprio MFMA -> barrier} interleave (T3 structure; reads are for THIS step only,
// no cross-step register prefetch).
// vmcnt LEDGER: step t reads only tile t. STG(t+3) issued during step t (A-half in phase A,
//   B-half in phase B). Prologue STG(0,1,2)=12 out -> vmcnt(8): tile0 landed, 1,2 in flight.
//   End of step t: in flight = t+2,t+3 (8 loads) -> vmcnt(8) drains tile t+1 (FIFO) -> barrier.
//   Tail: end of 28 -> vmcnt(8); 29 -> vmcnt(4); 30 -> vmcnt(0); 31 none.
//   WAR: STG(t+3) targets buf[(t-1)&3]; its readers' lgkm drained before step t-1's final
//   barrier, STG issued after it.
// MODE 0: qkv epilogue -> per-head layout (+bias, V transposed). MODE 1: fp32 out + bias.
template <int MODE>
__global__ __launch_bounds__(512) void k_gemm(
    const u16* __restrict__ A, const u16* __restrict__ Bw,
    const float* __restrict__ b0, const float* __restrict__ b1, const float* __restrict__ b2,
    u16* __restrict__ oq, float* __restrict__ of) {
  __shared__ alignas(16) u16 lds[4][16384];  // [buf][A:0..8191 | B:8192..16383]
  const int tid = threadIdx.x;
  const int l = tid & 63, w = tid >> 6;
  const int lo = l & 15, hi = l >> 4;
  const int wr = w >> 2, wc = w & 3;

  // bijective XCD swizzle (nwg % 8 == 0 for both grids)
  const int nbx = gridDim.x;
  const int nb = nbx * gridDim.y;
  const int bid = blockIdx.y * nbx + blockIdx.x;
  const int ord = (bid & 7) * (nb >> 3) + (bid >> 3);
  const int tn = (ord % nbx) * 256, tm = (ord / nbx) * 256;

  // staging lane map: pre-swizzled global source, linear LDS dest (lane*16B)
  const int sl = (tid & 7) ^ ((tid >> 3) & 7);   // logical slot this lane's dest holds
  const int srow = 2 * (tid >> 3) + (sl >> 2);   // row within half-tile (q=0); q=1 adds 128
  const int scol = (sl & 3) * 8;
  const u16* gA = A + (size_t)(tm + srow) * 1024 + scol;
  const u16* gB = Bw + (size_t)(tn + srow) * 1024 + scol;
  u16* dst = &lds[0][0] + tid * 8;

  // fragment-read lane constants (same involution)
  const int p7 = (lo >> 1) & 7;
  const int slr = ((lo & 1) * 4 + hi) ^ p7;
  const int aoff = wr * 4096 + (lo >> 1) * 64 + slr * 8;
  const int boff = 8192 + wc * 2048 + (lo >> 1) * 64 + slr * 8;

  f32x4 acc[8][4];
#pragma unroll
  for (int i = 0; i < 8; ++i)
#pragma unroll
    for (int j = 0; j < 4; ++j) acc[i][j] = (f32x4){0.f, 0.f, 0.f, 0.f};

  b16x8 af[8], bf[4];

#define STG_A(t) { const int kc = (t) * 32; u16* d = dst + ((t) & 3) * 16384; \
    gl2lds16(gA + kc, d);  gl2lds16(gA + 131072 + kc, d + 4096); }
#define STG_B(t) { const int kc = (t) * 32; u16* d = dst + ((t) & 3) * 16384; \
    gl2lds16(gB + kc, d + 8192);  gl2lds16(gB + 131072 + kc, d + 12288); }
// phase A: A-rowtiles 0-3 + all 4 B-frags (8 ds_read_b128), 16 MFMA (i=0..3)
#define PHA(bi) { const u16* _b = &lds[0][0] + (bi) * 16384; \
    _Pragma("unroll") for (int _i = 0; _i < 4; ++_i) af[_i] = *(const b16x8*)(_b + aoff + _i * 512); \
    _Pragma("unroll") for (int _j = 0; _j < 4; ++_j) bf[_j] = *(const b16x8*)(_b + boff + _j * 512); \
    __builtin_amdgcn_s_barrier(); \
    asm volatile("s_waitcnt lgkmcnt(0)" ::: "memory"); \
    __builtin_amdgcn_sched_barrier(0); \
    __builtin_amdgcn_s_setprio(1); \
    _Pragma("unroll") for (int _i = 0; _i < 4; ++_i) \
    _Pragma("unroll") for (int _j = 0; _j < 4; ++_j) \
      acc[_i][_j] = __builtin_amdgcn_mfma_f32_16x16x32_bf16(af[_i], bf[_j], acc[_i][_j], 0, 0, 0); \
    __builtin_amdgcn_s_setprio(0); \
    __builtin_amdgcn_s_barrier(); }
// phase B: A-rowtiles 4-7 (4 ds_read_b128), B reused from regs, 16 MFMA (i=4..7)
#define PHB(bi) { const u16* _b = &lds[0][0] + (bi) * 16384; \
    _Pragma("unroll") for (int _i = 4; _i < 8; ++_i) af[_i] = *(const b16x8*)(_b + aoff + _i * 512); \
    __builtin_amdgcn_s_barrier(); \
    asm volatile("s_waitcnt lgkmcnt(0)" ::: "memory"); \
    __builtin_amdgcn_sched_barrier(0); \
    __builtin_amdgcn_s_setprio(1); \
    _Pragma("unroll") for (int _i = 4; _i < 8; ++_i) \
    _Pragma("unroll") for (int _j = 0; _j < 4; ++_j) \
      acc[_i][_j] = __builtin_amdgcn_mfma_f32_16x16x32_bf16(af[_i], bf[_j], acc[_i][_j], 0, 0, 0); \
    __builtin_amdgcn_s_setprio(0); }
#define WV(n) { asm volatile("s_waitcnt vmcnt(" #n ")" ::: "memory"); \
    __builtin_amdgcn_s_barrier(); asm volatile("" ::: "memory"); }

  STG_A(0) STG_B(0) STG_A(1) STG_B(1) STG_A(2) STG_B(2)
  asm volatile("s_waitcnt vmcnt(8)" ::: "memory");  // tile 0 landed; 1,2 in flight
  __builtin_amdgcn_s_barrier();
  asm volatile("" ::: "memory");

#pragma unroll 4
  for (int kt = 0; kt < 28; ++kt) {
    STG_A(kt + 3)
    PHA(kt & 3)
    STG_B(kt + 3)
    PHB(kt & 3)
    WV(8)             // tile kt+1 drained; kt+2,kt+3 (8 loads) in flight
  }
  // tail: steps 28..31; entry invariant: tile 28 landed, 29,30 in flight
  STG_A(31) PHA(0) STG_B(31) PHB(0) WV(8)   // step 28: tile 29 landed; 30,31 in flight
  PHA(1) PHB(1) WV(4)                       // step 29: tile 30 landed; 31 in flight
  PHA(2) PHB(2) WV(0)                       // step 30: tile 31 landed
  PHA(3) PHB(3)                             // step 31
#undef STG_A
#undef STG_B
#undef PHA
#undef PHB
#undef WV

  if (MODE == 0) {
    const size_t G = 67108864;  // elements per q/k/v plane
    const int g = tn >> 10;     // 0:q 1:k 2:v (256 | 1024 -> uniform per block)
    const float* bias = (g == 0) ? b0 : (g == 1) ? b1 : b2;
    const int nn0 = (tn & 1023) + wc * 64;
#pragma unroll
    for (int j = 0; j < 4; ++j) {
      const int nn = nn0 + j * 16 + lo;
      const float bv = bias[nn];
      const int h = nn >> 5, hd = nn & 31;
      if (g < 2) {
#pragma unroll
        for (int i = 0; i < 8; ++i) {
          const int m0 = tm + wr * 128 + i * 16 + hi * 4;  // row = (l>>4)*4 + reg
          const int b = m0 >> 6, s0 = m0 & 63;
          const size_t base = (size_t)g * G + ((size_t)(b * 32 + h) * 64 + s0) * 32 + hd;
#pragma unroll
          for (int r = 0; r < 4; ++r) oq[base + (size_t)r * 32] = f2b(acc[i][j][r] + bv);
        }
      } else {
#pragma unroll
        for (int i = 0; i < 8; ++i) {
          const int m0 = tm + wr * 128 + i * 16 + hi * 4;
          const int b = m0 >> 6, s0 = m0 & 63;
          ushort4 pk;
          pk.x = f2b(acc[i][j][0] + bv);
          pk.y = f2b(acc[i][j][1] + bv);
          pk.z = f2b(acc[i][j][2] + bv);
          pk.w = f2b(acc[i][j][3] + bv);
          *(ushort4*)(oq + 2 * G + ((size_t)(b * 32 + h) * 32 + hd) * 64 + s0) = pk;
        }
      }
    }
  } else {
#pragma unroll
    for (int j = 0; j < 4; ++j) {
      const int n = tn + wc * 64 + j * 16 + lo;
      const float bv = b0[n];
#pragma unroll
      for (int i = 0; i < 8; ++i) {
        const int m0 = tm + wr * 128 + i * 16 + hi * 4;
#pragma unroll
        for (int r = 0; r < 4; ++r) of[(size_t)(m0 + r) * 1024 + n] = acc[i][j][r] + bv;
      }
    }
  }
}

// ---------------- attention: one (b,h) per 256-thread block, wave w owns q-rows [w*16, w*16+16) --
// Board layout [q>>2][col(240)][q&3] u16: MFMA tile stores become ONE ds_write_b64 (4 rows,
// same col) instead of 4 scalar stores. pl (P matrix) overlays board (extra barrier). V hoisted.
__global__ __launch_bounds__(256) void k_attn(
    const u16* __restrict__ qkv, const u16* __restrict__ rq,
    const u16* __restrict__ rk, u16* __restrict__ att) {
  __shared__ alignas(16) u16 board[16 * 240 * 4];  // 30720 B; pl overlays first 9216 B
  u16* pl = board;                                 // [64][72] row-major
  const int l = threadIdx.x & 63, w = threadIdx.x >> 6;
  const int lo = l & 15, hi = l >> 4;
  const int b = blockIdx.x, h = blockIdx.y;
  const size_t G = 67108864;
  const u16* qp = qkv + (size_t)(b * 32 + h) * 2048;          // [64][32]
  const u16* kp = qkv + G + (size_t)(b * 32 + h) * 2048;      // [64][32]
  const u16* vp = qkv + 2 * G + (size_t)(b * 32 + h) * 2048;  // V^T [32][64]

  // Q fragment (A-operand): rows w*16+lo, d = hi*8..+8
  b16x8 qf = *(const b16x8*)(qp + (w * 16 + lo) * 32 + hi * 8);
  // hoisted V fragments (used phase 8; HBM latency hides under board GEMMs)
  b16x8 v00 = *(const b16x8*)(vp + lo * 64 + hi * 8);
  b16x8 v01 = *(const b16x8*)(vp + lo * 64 + 32 + hi * 8);
  b16x8 v10 = *(const b16x8*)(vp + (16 + lo) * 64 + hi * 8);
  b16x8 v11 = *(const b16x8*)(vp + (16 + lo) * 64 + 32 + hi * 8);

  // Phase 1: QK^T  (B-operand: lane holds K[kt*16+lo][d contiguous])
  f32x4 s0[4];
#pragma unroll
  for (int kt = 0; kt < 4; ++kt) {
    b16x8 kf = *(const b16x8*)(kp + (kt * 16 + lo) * 32 + hi * 8);
    f32x4 z = (f32x4){0.f, 0.f, 0.f, 0.f};
    s0[kt] = __builtin_amdgcn_mfma_f32_16x16x32_bf16(qf, kf, z, 0, 0, 0);
  }

  // Phase 2: Bq = Q @ Rq[h]^T -> board rows (w*4+hi), packed b64 stores (wave-private rows)
  const u16* rqh = rq + (size_t)h * 7680;  // 240*32
#pragma unroll
  for (int nt = 0; nt < 15; ++nt) {
    b16x8 rf = *(const b16x8*)(rqh + (nt * 16 + lo) * 32 + hi * 8);
    f32x4 z = (f32x4){0.f, 0.f, 0.f, 0.f};
    f32x4 c = __builtin_amdgcn_mfma_f32_16x16x32_bf16(qf, rf, z, 0, 0, 0);
    ushort4 pk;
    pk.x = f2b(c[0]); pk.y = f2b(c[1]); pk.z = f2b(c[2]); pk.w = f2b(c[3]);
    *(ushort4*)(board + (((w * 4 + hi) * 240 + nt * 16 + lo) << 2)) = pk;
  }
  // Phase 3: gather Bq (reads only this wave's rows; same-wave LDS RAW -> lgkmcnt)
#pragma unroll
  for (int kt = 0; kt < 4; ++kt)
#pragma unroll
    for (int r = 0; r < 4; ++r) {
      int q = w * 16 + hi * 4 + r, k = kt * 16 + lo;
      int rel = 15 * ((q >> 3) - (k >> 3) + 7) + (q & 7) - (k & 7) + 7;
      s0[kt][r] += b2f(board[((w * 4 + hi) * 240 + rel) * 4 + r]);
    }

  // Phase 4: Bk = K @ Rk[h]^T -> board rows (w*4+hi) (overwrites own rows only)
  b16x8 kfa = *(const b16x8*)(kp + (w * 16 + lo) * 32 + hi * 8);
  const u16* rkh = rk + (size_t)h * 7680;
#pragma unroll
  for (int nt = 0; nt < 15; ++nt) {
    b16x8 rf = *(const b16x8*)(rkh + (nt * 16 + lo) * 32 + hi * 8);
    f32x4 z = (f32x4){0.f, 0.f, 0.f, 0.f};
    f32x4 c = __builtin_amdgcn_mfma_f32_16x16x32_bf16(kfa, rf, z, 0, 0, 0);
    ushort4 pk;
    pk.x = f2b(c[0]); pk.y = f2b(c[1]); pk.z = f2b(c[2]); pk.w = f2b(c[3]);
    *(ushort4*)(board + (((w * 4 + hi) * 240 + nt * 16 + lo) << 2)) = pk;
  }
  __syncthreads();  // Bk board read cross-wave below
  // Phase 5: gather Bk (indexed by k row -> all rows)
#pragma unroll
  for (int kt = 0; kt < 4; ++kt)
#pragma unroll
    for (int r = 0; r < 4; ++r) {
      int q = w * 16 + hi * 4 + r, k = kt * 16 + lo;
      int rel = 15 * ((q >> 3) - (k >> 3) + 7) + (q & 7) - (k & 7) + 7;
      s0[kt][r] += b2f(board[((k >> 2) * 240 + rel) * 4 + (k & 3)]);
    }

  // Phase 6: scale + softmax (rows live in 16-lane groups; reduce over xor 1,2,4,8)
  const float sc = 0.17677669529663689f;  // 1/sqrt(32)
#pragma unroll
  for (int kt = 0; kt < 4; ++kt) s0[kt] *= sc;
  float p[4][4], rsum[4];
#pragma unroll
  for (int r = 0; r < 4; ++r) {
    float m = s0[0][r];
    m = fmaxf(m, s0[1][r]); m = fmaxf(m, s0[2][r]); m = fmaxf(m, s0[3][r]);
    m = fmaxf(m, __shfl_xor(m, 1));
    m = fmaxf(m, __shfl_xor(m, 2));
    m = fmaxf(m, __shfl_xor(m, 4));
    m = fmaxf(m, __shfl_xor(m, 8));
    float sum = 0.f;
#pragma unroll
    for (int kt = 0; kt < 4; ++kt) {
      float e = __expf(s0[kt][r] - m);
      p[kt][r] = e;
      sum += e;
    }
    sum += __shfl_xor(sum, 1);
    sum += __shfl_xor(sum, 2);
    sum += __shfl_xor(sum, 4);
    sum += __shfl_xor(sum, 8);
    rsum[r] = 1.f / sum;
  }

  __syncthreads();  // overlay guard: all board gathers done before pl overwrites board bytes

  // Phase 7: P -> LDS (wave-private rows; normalization deferred to output)
#pragma unroll
  for (int kt = 0; kt < 4; ++kt)
#pragma unroll
    for (int r = 0; r < 4; ++r) pl[(w * 16 + hi * 4 + r) * 72 + kt * 16 + lo] = f2b(p[kt][r]);

  // Phase 8: O = P @ V   (A: P rows w*16+lo; B: V^T rows hd, k contiguous)
  f32x4 o0 = (f32x4){0.f, 0.f, 0.f, 0.f}, o1 = (f32x4){0.f, 0.f, 0.f, 0.f};
  {
    b16x8 pa0 = *(const b16x8*)(pl + (w * 16 + lo) * 72 + hi * 8);
    b16x8 pa1 = *(const b16x8*)(pl + (w * 16 + lo) * 72 + 32 + hi * 8);
    o0 = __builtin_amdgcn_mfma_f32_16x16x32_bf16(pa0, v00, o0, 0, 0, 0);
    o1 = __builtin_amdgcn_mfma_f32_16x16x32_bf16(pa0, v10, o1, 0, 0, 0);
    o0 = __builtin_amdgcn_mfma_f32_16x16x32_bf16(pa1, v01, o0, 0, 0, 0);
    o1 = __builtin_amdgcn_mfma_f32_16x16x32_bf16(pa1, v11, o1, 0, 0, 0);
  }

  // Phase 9: write att[b][s][h*32+hd] (bf16), scaled by 1/rowsum
#pragma unroll
  for (int r = 0; r < 4; ++r) {
    int q = w * 16 + hi * 4 + r;
    size_t base = (size_t)(b * 64 + q) * 1024 + h * 32;
    att[base + lo] = f2b(o0[r] * rsum[r]);
    att[base + 16 + lo] = f2b(o1[r] * rsum[r]);
  }
}

extern "C" void kernel_launch(void* const* d_in, const int* in_sizes, int n_in,
                              void* d_out, int out_size, void* d_ws, size_t ws_size,
                              hipStream_t stream) {
  const float* x   = (const float*)d_in[0];
  const float* qw  = (const float*)d_in[1];
  const float* qb  = (const float*)d_in[2];
  const float* kw  = (const float*)d_in[3];
  const float* kb  = (const float*)d_in[4];
  const float* vw  = (const float*)d_in[5];
  const float* vb  = (const float*)d_in[6];
  const float* ow  = (const float*)d_in[7];
  const float* ob  = (const float*)d_in[8];
  const float* rqw = (const float*)d_in[9];
  const float* rkw = (const float*)d_in[10];

  // workspace layout (total 680,460,288 bytes)
  if (ws_size < 680460288ULL) return;  // diagnostic: leaves d_out zeroed -> absmax == max|ref|
  char* p = (char*)d_ws;
  u16* ws_x   = (u16*)p; p += (size_t)65536 * 1024 * 2;      // x bf16
  u16* ws_w   = (u16*)p; p += (size_t)3 * 1024 * 1024 * 2;   // qkv weights bf16 [3072][1024]
  u16* ws_wo  = (u16*)p; p += (size_t)1024 * 1024 * 2;       // out_w bf16
  u16* ws_rq  = (u16*)p; p += (size_t)32 * 240 * 32 * 2;     // Rq [h][r][d]
  u16* ws_rk  = (u16*)p; p += (size_t)32 * 240 * 32 * 2;     // Rk [h][r][d]
  u16* ws_qkv = (u16*)p; p += (size_t)3 * 67108864 * 2;      // q,k [b][h][s][hd]; v [b][h][hd][s]
  u16* ws_att = (u16*)p; p += (size_t)65536 * 1024 * 2;      // attention out [b*s][1024]

  k_cvt<<<32768, 256, 0, stream>>>(x, ws_x, 67108864L);
  k_cvt<<<512, 256, 0, stream>>>(qw, ws_w, 1048576L);
  k_cvt<<<512, 256, 0, stream>>>(kw, ws_w + 1048576, 1048576L);
  k_cvt<<<512, 256, 0, stream>>>(vw, ws_w + 2097152, 1048576L);
  k_cvt<<<512, 256, 0, stream>>>(ow, ws_wo, 1048576L);
  k_rpe<<<dim3(30, 32, 2), 256, 0, stream>>>(rqw, rkw, ws_rq, ws_rk);

  // QKV projection: 12 n-tiles x 256 m-tiles (nwg=3072, %8==0 for XCD swizzle)
  k_gemm<0><<<dim3(12, 256), 512, 0, stream>>>(ws_x, ws_w, qb, kb, vb, ws_qkv, nullptr);
  // attention: grid.x = b (fastest) so consecutive blocks reuse Rq[h]/Rk[h] in cache
  k_attn<<<dim3(1024, 32), 256, 0, stream>>>(ws_qkv, ws_rq, ws_rk, ws_att);
  // output projection: 4 n-tiles x 256 m-tiles (nwg=1024)
  k_gemm<1><<<dim3(4, 256), 512, 0, stream>>>(ws_att, ws_wo, ob, nullptr, nullptr, nullptr,
                                              (float*)d_out);
}